// Round 1
// 228.174 us; speedup vs baseline: 1.0129x; 1.0129x over previous
//
#include <hip/hip_runtime.h>
#include <stdint.h>

// ScopeWiseSum via bf16 MFMA, register-resident A-fragments (no e/m LDS staging).
// out[s,d,b,j] = log( sum_k exp(x[b,k]-m_b) * w[k,j] ) + m_b,  w = acc / colsum(acc).
//
// R2 post-mortem: 84 us, all pipes <40% -> latency-bound at 3 blocks/CU (28.6 KB LDS).
// R3: lanes load their MFMA A-frag directly from global; row-max via shfl_xor(16/32);
// LDS = weight phase only; ROWS=128, launch_bounds(256,8) -> 8 blocks/CU.
// R4 (this round): swap MFMA operands -> C^T layout. A/B frags share the same lane
// layout (lane&15 = m/n, quad*8+e = k), so mfma(bfrag, afrag) computes the transpose
// with zero data movement. Lane then holds out[b=rt*16+l15][j=jt*16+quad*4..+3]:
//  - epilogue becomes 4x global_store_dwordx4 (was 16x scalar dword, 4x coalescing)
//  - the 8 ds_bpermute (__shfl of row-max) vanish: lane's own mrow[i] IS row l15's max
//  - wt_lds pitch 32->40 shorts: B-frag ds_read_b128 was 8-way bank conflict at 64B
//    stride; 80B stride hits all 32 banks (~2-way aliasing, free per m136).

#define THREADS 256
#define ROWS    128      // rows per block -> 8192 blocks
#define WPITCH  40       // wt_lds pitch in shorts (80 B: bank-conflict-free b128 reads)

typedef __attribute__((ext_vector_type(8))) short short8;   // MFMA A/B frag (8 bf16)
typedef __attribute__((ext_vector_type(4))) float f32x4;    // MFMA C/D frag
typedef __attribute__((ext_vector_type(4))) int   i32x4;

__device__ __forceinline__ uint32_t pack2_bf16(float lo, float hi) {
    uint32_t ul = __builtin_bit_cast(uint32_t, lo);
    uint32_t uh = __builtin_bit_cast(uint32_t, hi);
    ul = (ul + 0x7fffu + ((ul >> 16) & 1u)) >> 16;   // RNE to bf16
    uh = (uh + 0x7fffu + ((uh >> 16) & 1u)) >> 16;
    return ul | (uh << 16);
}

__device__ __forceinline__ unsigned short bf16_1(float v) {
    uint32_t u = __builtin_bit_cast(uint32_t, v);
    return (unsigned short)((u + 0x7fffu + ((u >> 16) & 1u)) >> 16);
}

__global__ __launch_bounds__(THREADS, 8) void sws_kernel(
    const float* __restrict__ x,
    const float* __restrict__ acc,
    float* __restrict__ out)
{
    __shared__ float w_f32[32 * 32];                        // raw acc tile
    __shared__ float inv_lds[32];                           // 1/colsum
    __shared__ __align__(16) unsigned short wt_lds[32 * WPITCH]; // bf16 w^T [j][k]

    const int t    = threadIdx.x;
    const int blk  = blockIdx.x;
    const int sd   = blk >> 3;            // 8 row-tiles of 128 per (s,d)
    const int lane = t & 63;
    const int wv   = t >> 6;
    const int l15  = lane & 15;
    const int quad = lane >> 4;

    // ---- x loads: lane's own A-frag bytes. rt = wv*2+i, row = rt*16+l15,
    //      k = quad*8..+7 -> two consecutive float4 at (row*8 + quad*2) ----
    const float4* x4 = (const float4*)(x + (size_t)blk * ROWS * 32);
    float4 xv[4];
#pragma unroll
    for (int i = 0; i < 2; ++i) {
        int f4 = ((wv * 2 + i) * 16 + l15) * 8 + quad * 2;
        xv[2 * i]     = x4[f4];
        xv[2 * i + 1] = x4[f4 + 1];
    }

    // ---- weight phase (only LDS user): load acc, colsum, normalize, bf16 w^T ----
    const float4 a4 = ((const float4*)(acc + (size_t)sd * 1024))[t];  // k=t>>3, j=(t&7)*4..+3
    *((float4*)&w_f32[t * 4]) = a4;
    __syncthreads();
    if (t < 32) {
        float s = 0.f;
#pragma unroll
        for (int k = 0; k < 32; ++k) s += w_f32[k * 32 + t];  // bank t: conflict-free
        inv_lds[t] = 1.0f / s;
    }
    __syncthreads();
    {
        const int k = t >> 3, j0 = (t & 7) * 4;
        const float4 inv4 = *((const float4*)&inv_lds[j0]);
        wt_lds[(j0 + 0) * WPITCH + k] = bf16_1(a4.x * inv4.x);
        wt_lds[(j0 + 1) * WPITCH + k] = bf16_1(a4.y * inv4.y);
        wt_lds[(j0 + 2) * WPITCH + k] = bf16_1(a4.z * inv4.z);
        wt_lds[(j0 + 3) * WPITCH + k] = bf16_1(a4.w * inv4.w);
    }

    // ---- e phase: in-register row max (across quads), exp, pack bf16 A-frags ----
    float  mrow[2];
    short8 afrag[2];
#pragma unroll
    for (int i = 0; i < 2; ++i) {
        float4 a = xv[2 * i], b = xv[2 * i + 1];
        float m = fmaxf(fmaxf(fmaxf(a.x, a.y), fmaxf(a.z, a.w)),
                        fmaxf(fmaxf(b.x, b.y), fmaxf(b.z, b.w)));
        m = fmaxf(m, __shfl_xor(m, 16, 64));   // combine the 4 quads holding this row
        m = fmaxf(m, __shfl_xor(m, 32, 64));
        mrow[i] = m;
        i32x4 pk;
        pk[0] = (int)pack2_bf16(__expf(a.x - m), __expf(a.y - m));
        pk[1] = (int)pack2_bf16(__expf(a.z - m), __expf(a.w - m));
        pk[2] = (int)pack2_bf16(__expf(b.x - m), __expf(b.y - m));
        pk[3] = (int)pack2_bf16(__expf(b.z - m), __expf(b.w - m));
        afrag[i] = __builtin_bit_cast(short8, pk);
    }
    __syncthreads();   // wt_lds ready

    // ---- B-frags + swapped MFMA: D = (w^T)·(e^T) = C^T ----
    short8 bfrag[2];
#pragma unroll
    for (int jt = 0; jt < 2; ++jt)
        bfrag[jt] = *(const short8*)&wt_lds[(jt * 16 + l15) * WPITCH + quad * 8];

    f32x4 cacc[2][2];
#pragma unroll
    for (int i = 0; i < 2; ++i)
#pragma unroll
        for (int jt = 0; jt < 2; ++jt)
            cacc[i][jt] = __builtin_amdgcn_mfma_f32_16x16x32_bf16(
                bfrag[jt], afrag[i], (f32x4){0.f, 0.f, 0.f, 0.f}, 0, 0, 0);

    // ---- epilogue: C^T layout -> lane holds out[b = rt*16+l15][j = jt*16+quad*4+r],
    //      r=0..3 consecutive -> float4 store; mrow[i] is already row b's max ----
    float* ob = out + (size_t)blk * ROWS * 32;
#pragma unroll
    for (int i = 0; i < 2; ++i) {
        float* orow = ob + (size_t)((wv * 2 + i) * 16 + l15) * 32;
        const float mr = mrow[i];
#pragma unroll
        for (int jt = 0; jt < 2; ++jt) {
            f32x4 c = cacc[i][jt];
            float4 o;
            o.x = __logf(c[0]) + mr;
            o.y = __logf(c[1]) + mr;
            o.z = __logf(c[2]) + mr;
            o.w = __logf(c[3]) + mr;
            *(float4*)(orow + jt * 16 + quad * 4) = o;
        }
    }
}

extern "C" void kernel_launch(void* const* d_in, const int* in_sizes, int n_in,
                              void* d_out, int out_size, void* d_ws, size_t ws_size,
                              hipStream_t stream) {
    const float* x   = (const float*)d_in[0];   // [128,8,1024,32] fp32
    const float* acc = (const float*)d_in[1];   // [128,8,32,32]  fp32
    float* out = (float*)d_out;                 // [128,8,1024,32] fp32

    dim3 grid(8192);   // 1024 (s,d) pairs * 8 row-tiles of 128 rows
    dim3 block(THREADS);
    hipLaunchKernelGGL(sws_kernel, grid, block, 0, stream, x, acc, out);
}